// Round 1
// baseline (685.020 us; speedup 1.0000x reference)
//
#include <hip/hip_runtime.h>

// 3D reaction-diffusion tumor solver, 160^3 f32 grid, 30 explicit Euler steps.
// c_{t+1} = clip(c + (D*lap(c) + rho*c*(1-c) - 2*therapy*c) * dt/steps, 0, 1)
// lap = 7-point stencil with zero ("SAME") padding.

#define NX 160
#define NY 160
#define NZ 160
#define NXQ (NX / 4)            // 40 float4 groups per row
#define NTHREADS (NZ * NY * NXQ) // 1,024,000

__global__ __launch_bounds__(256) void therapy_step(
    const float* __restrict__ src,
    const float* __restrict__ ther,
    float* __restrict__ dst,
    const float* __restrict__ Dp,
    const float* __restrict__ rhop,
    const float* __restrict__ dtp,
    const int* __restrict__ stepsp)
{
    const int tid = blockIdx.x * blockDim.x + threadIdx.x;
    if (tid >= NTHREADS) return;

    const int xq = tid % NXQ;
    const int t2 = tid / NXQ;
    const int y  = t2 % NY;
    const int z  = t2 / NY;
    const int base = tid * 4;   // == z*NY*NX + y*NX + 4*xq (layout is contiguous)

    const float4 zero4 = make_float4(0.f, 0.f, 0.f, 0.f);

    const float4 cc = *reinterpret_cast<const float4*>(src + base);
    const float4 tm = *reinterpret_cast<const float4*>(ther + base);

    const float4 ymv = (y > 0)      ? *reinterpret_cast<const float4*>(src + base - NX)      : zero4;
    const float4 ypv = (y < NY - 1) ? *reinterpret_cast<const float4*>(src + base + NX)      : zero4;
    const float4 zmv = (z > 0)      ? *reinterpret_cast<const float4*>(src + base - NX * NY) : zero4;
    const float4 zpv = (z < NZ - 1) ? *reinterpret_cast<const float4*>(src + base + NX * NY) : zero4;

    const float xl = (xq > 0)       ? src[base - 1] : 0.f;
    const float xr = (xq < NXQ - 1) ? src[base + 4] : 0.f;

    const float D       = *Dp;
    const float rho     = *rhop;
    const float delta_t = *dtp / (float)(*stepsp);

    // Laplacian per lane of the float4
    const float lap0 = xl   + cc.y + ymv.x + ypv.x + zmv.x + zpv.x - 6.f * cc.x;
    const float lap1 = cc.x + cc.z + ymv.y + ypv.y + zmv.y + zpv.y - 6.f * cc.y;
    const float lap2 = cc.y + cc.w + ymv.z + ypv.z + zmv.z + zpv.z - 6.f * cc.z;
    const float lap3 = cc.z + xr   + ymv.w + ypv.w + zmv.w + zpv.w - 6.f * cc.w;

    float4 o;
    {
        const float g = D * lap0 + rho * cc.x * (1.f - cc.x) - 2.f * tm.x * cc.x;
        o.x = fminf(fmaxf(cc.x + g * delta_t, 0.f), 1.f);
    }
    {
        const float g = D * lap1 + rho * cc.y * (1.f - cc.y) - 2.f * tm.y * cc.y;
        o.y = fminf(fmaxf(cc.y + g * delta_t, 0.f), 1.f);
    }
    {
        const float g = D * lap2 + rho * cc.z * (1.f - cc.z) - 2.f * tm.z * cc.z;
        o.z = fminf(fmaxf(cc.z + g * delta_t, 0.f), 1.f);
    }
    {
        const float g = D * lap3 + rho * cc.w * (1.f - cc.w) - 2.f * tm.w * cc.w;
        o.w = fminf(fmaxf(cc.w + g * delta_t, 0.f), 1.f);
    }

    *reinterpret_cast<float4*>(dst + base) = o;
}

extern "C" void kernel_launch(void* const* d_in, const int* in_sizes, int n_in,
                              void* d_out, int out_size, void* d_ws, size_t ws_size,
                              hipStream_t stream) {
    const float* c_init = (const float*)d_in[0];
    const float* Dp     = (const float*)d_in[1];
    const float* rhop   = (const float*)d_in[2];
    const float* dtp    = (const float*)d_in[3];
    const float* ther   = (const float*)d_in[4];
    const int*   stepsp = (const int*)d_in[5];

    float* out = (float*)d_out;
    float* wsA = (float*)d_ws;   // one ping-pong buffer (16.4 MB)

    const dim3 block(256);
    const dim3 grid(NTHREADS / 256);   // 4000 blocks, exact (1,024,000 threads)

    // 30 steps (reference setup: steps=30; launch count must be capture-static).
    // Even steps write ws, odd steps write d_out -> step 29 (last) lands in d_out.
    const float* src = c_init;
    for (int i = 0; i < 30; ++i) {
        float* dst = (i & 1) ? out : wsA;
        therapy_step<<<grid, block, 0, stream>>>(src, ther, dst, Dp, rhop, dtp, stepsp);
        src = dst;
    }
}

// Round 2
// 476.209 us; speedup vs baseline: 1.4385x; 1.4385x over previous
//
#include <hip/hip_runtime.h>

// 3D reaction-diffusion tumor solver, 160^3 f32 grid, 30 explicit Euler steps.
// c_{t+1} = clip(c + (D*lap(c) + rho*c*(1-c) - 2*therapy*c) * dt/steps, 0, 1)
// lap = 7-point stencil, zero ("SAME") padding.
//
// R2: straight-line loads (clamped addr + cndmask select, no branches) and
// 2 independent float4 groups per thread (z and z+80) for 2x memory-level
// parallelism. Grid: 2000 blocks x 256 threads.

#define NX 160
#define NY 160
#define NZ 160
#define NXQ (NX / 4)              // 40 float4 groups per row
#define NPLANE (NX * NY)          // 25600 floats per z-plane
#define NGROUPS (NZ * NY * NXQ)   // 1,024,000 float4 groups
#define NTHREADS (NGROUPS / 2)    // 512,000 threads, 2 groups each

__device__ __forceinline__ float4 ld4(const float* p) {
    return *reinterpret_cast<const float4*>(p);
}

__global__ __launch_bounds__(256) void therapy_step(
    const float* __restrict__ src,
    const float* __restrict__ ther,
    float* __restrict__ dst,
    const float* __restrict__ Dp,
    const float* __restrict__ rhop,
    const float* __restrict__ dtp,
    const int* __restrict__ stepsp)
{
    const int tid = blockIdx.x * blockDim.x + threadIdx.x;

    const int xq = tid % NXQ;
    const int t2 = tid / NXQ;
    const int y  = t2 % NY;
    const int z0 = t2 / NY;             // 0..79
    const int base0 = tid * 4;          // group 0: z in [0,80)
    const int base1 = base0 + 80 * NPLANE;  // group 1: z in [80,160)

    // Boundary-safe offsets (always-valid addresses; values masked later).
    const int offym = (y > 0)        ? -NX : 0;
    const int offyp = (y < NY - 1)   ?  NX : 0;
    const int offxl = (xq > 0)       ? -1  : 0;
    const int offxr = (xq < NXQ - 1) ?  4  : 3;
    const int offzm0 = (z0 > 0)      ? -NPLANE : 0;   // group0 z-1 (z0==0 masked)
    const int offzp1 = (z0 < 79)     ?  NPLANE : 0;   // group1 z+1 (z1==159 masked)

    // ---- issue ALL loads up front (straight-line, max loads in flight) ----
    const float4 cc0 = ld4(src + base0);
    const float4 cc1 = ld4(src + base1);
    float4 ym0 = ld4(src + base0 + offym);
    float4 ym1 = ld4(src + base1 + offym);
    float4 yp0 = ld4(src + base0 + offyp);
    float4 yp1 = ld4(src + base1 + offyp);
    float4 zm0 = ld4(src + base0 + offzm0);
    const float4 zm1 = ld4(src + base1 - NPLANE);     // z1-1 >= 79: always valid
    const float4 zp0 = ld4(src + base0 + NPLANE);     // z0+1 <= 80: always valid
    float4 zp1 = ld4(src + base1 + offzp1);
    float xl0 = src[base0 + offxl];
    float xl1 = src[base1 + offxl];
    float xr0 = src[base0 + offxr];
    float xr1 = src[base1 + offxr];
    const float4 tm0 = ld4(ther + base0);
    const float4 tm1 = ld4(ther + base1);

    // scalar params (wave-uniform -> s_load)
    const float D       = *Dp;
    const float rho     = *rhop;
    const float delta_t = *dtp / (float)(*stepsp);

    const float4 zero4 = make_float4(0.f, 0.f, 0.f, 0.f);

    // ---- boundary masking (v_cndmask, no branches) ----
    if (y == 0)        { ym0 = zero4; ym1 = zero4; }
    if (y == NY - 1)   { yp0 = zero4; yp1 = zero4; }
    if (z0 == 0)       { zm0 = zero4; }
    if (z0 == 79)      { zp1 = zero4; }
    if (xq == 0)       { xl0 = 0.f; xl1 = 0.f; }
    if (xq == NXQ - 1) { xr0 = 0.f; xr1 = 0.f; }

    // ---- group 0 ----
    {
        const float lap0 = xl0   + cc0.y + ym0.x + yp0.x + zm0.x + zp0.x - 6.f * cc0.x;
        const float lap1 = cc0.x + cc0.z + ym0.y + yp0.y + zm0.y + zp0.y - 6.f * cc0.y;
        const float lap2 = cc0.y + cc0.w + ym0.z + yp0.z + zm0.z + zp0.z - 6.f * cc0.z;
        const float lap3 = cc0.z + xr0   + ym0.w + yp0.w + zm0.w + zp0.w - 6.f * cc0.w;
        float4 o;
        float g;
        g = D * lap0 + rho * cc0.x * (1.f - cc0.x) - 2.f * tm0.x * cc0.x;
        o.x = fminf(fmaxf(cc0.x + g * delta_t, 0.f), 1.f);
        g = D * lap1 + rho * cc0.y * (1.f - cc0.y) - 2.f * tm0.y * cc0.y;
        o.y = fminf(fmaxf(cc0.y + g * delta_t, 0.f), 1.f);
        g = D * lap2 + rho * cc0.z * (1.f - cc0.z) - 2.f * tm0.z * cc0.z;
        o.z = fminf(fmaxf(cc0.z + g * delta_t, 0.f), 1.f);
        g = D * lap3 + rho * cc0.w * (1.f - cc0.w) - 2.f * tm0.w * cc0.w;
        o.w = fminf(fmaxf(cc0.w + g * delta_t, 0.f), 1.f);
        *reinterpret_cast<float4*>(dst + base0) = o;
    }
    // ---- group 1 ----
    {
        const float lap0 = xl1   + cc1.y + ym1.x + yp1.x + zm1.x + zp1.x - 6.f * cc1.x;
        const float lap1 = cc1.x + cc1.z + ym1.y + yp1.y + zm1.y + zp1.y - 6.f * cc1.y;
        const float lap2 = cc1.y + cc1.w + ym1.z + yp1.z + zm1.z + zp1.z - 6.f * cc1.z;
        const float lap3 = cc1.z + xr1   + ym1.w + yp1.w + zm1.w + zp1.w - 6.f * cc1.w;
        float4 o;
        float g;
        g = D * lap0 + rho * cc1.x * (1.f - cc1.x) - 2.f * tm1.x * cc1.x;
        o.x = fminf(fmaxf(cc1.x + g * delta_t, 0.f), 1.f);
        g = D * lap1 + rho * cc1.y * (1.f - cc1.y) - 2.f * tm1.y * cc1.y;
        o.y = fminf(fmaxf(cc1.y + g * delta_t, 0.f), 1.f);
        g = D * lap2 + rho * cc1.z * (1.f - cc1.z) - 2.f * tm1.z * cc1.z;
        o.z = fminf(fmaxf(cc1.z + g * delta_t, 0.f), 1.f);
        g = D * lap3 + rho * cc1.w * (1.f - cc1.w) - 2.f * tm1.w * cc1.w;
        o.w = fminf(fmaxf(cc1.w + g * delta_t, 0.f), 1.f);
        *reinterpret_cast<float4*>(dst + base1) = o;
    }
}

extern "C" void kernel_launch(void* const* d_in, const int* in_sizes, int n_in,
                              void* d_out, int out_size, void* d_ws, size_t ws_size,
                              hipStream_t stream) {
    const float* c_init = (const float*)d_in[0];
    const float* Dp     = (const float*)d_in[1];
    const float* rhop   = (const float*)d_in[2];
    const float* dtp    = (const float*)d_in[3];
    const float* ther   = (const float*)d_in[4];
    const int*   stepsp = (const int*)d_in[5];

    float* out = (float*)d_out;
    float* wsA = (float*)d_ws;   // ping-pong buffer (16.4 MB)

    const dim3 block(256);
    const dim3 grid(NTHREADS / 256);   // 2000 blocks

    // 30 steps; even steps write ws, odd steps write d_out -> step 29 in d_out.
    const float* src = c_init;
    for (int i = 0; i < 30; ++i) {
        float* dst = (i & 1) ? out : wsA;
        therapy_step<<<grid, block, 0, stream>>>(src, ther, dst, Dp, rhop, dtp, stepsp);
        src = dst;
    }
}